// Round 1
// 486.616 us; speedup vs baseline: 1.0104x; 1.0104x over previous
//
#include <hip/hip_runtime.h>
#include <math.h>

// BeliveMapsNMS: 7x7 same-padded max-pool NMS on [32,4,512,512] f32.
// Outputs (concat flat): mask(0/1 f32), scores_abs, scores_rel.
// Write-bound: 403 MB out + 134 MB in. Structure: full-row tiles (512 x 16),
// horizontal 7-max in registers via wave shuffles (van Herk), rowmax in LDS,
// vertical 7-max van Herk from LDS, nontemporal stores.
// R1: register-prefetch all Phase-A row loads (kill serial HBM latency),
//     issue Phase-B ctr loads pre-barrier, XCD-chunked block swizzle.

#define H 512
#define W 512
#define PLANE_ELEMS (H * W)   // 262144
#define TH 16                 // output rows per block
#define LROWS (TH + 6)        // 22 loaded rows
#define NEG_INF (-INFINITY)

typedef float v4f __attribute__((ext_vector_type(4)));  // native vec for nontemporal

__device__ __forceinline__ float4 vmax4(float4 a, float4 b) {
    return make_float4(fmaxf(a.x, b.x), fmaxf(a.y, b.y), fmaxf(a.z, b.z), fmaxf(a.w, b.w));
}

__device__ __forceinline__ void nt_store4(float* p, float a, float b, float c, float d) {
    v4f v = {a, b, c, d};
    __builtin_nontemporal_store(v, (v4f*)p);
}

// ---------------- Pass 1: per-plane max ----------------
__global__ __launch_bounds__(256) void vmax_kernel(const float* __restrict__ in,
                                                   unsigned int* __restrict__ vmax_bits) {
    const int q = blockIdx.x;      // 4 quarters
    const int plane = blockIdx.y;  // 128 planes
    const float4* p = (const float4*)(in + (size_t)plane * PLANE_ELEMS + q * (PLANE_ELEMS / 4));
    float m = 0.0f;  // inputs in [0,1): non-negative
    const int nvec = PLANE_ELEMS / 4 / 4;  // 16384 float4 per quarter
    for (int i = threadIdx.x; i < nvec; i += 256) {
        float4 v = p[i];
        m = fmaxf(m, fmaxf(fmaxf(v.x, v.y), fmaxf(v.z, v.w)));
    }
    #pragma unroll
    for (int o = 32; o > 0; o >>= 1) m = fmaxf(m, __shfl_down(m, o, 64));
    __shared__ float s[4];
    if ((threadIdx.x & 63) == 0) s[threadIdx.x >> 6] = m;
    __syncthreads();
    if (threadIdx.x == 0) {
        m = fmaxf(fmaxf(s[0], s[1]), fmaxf(s[2], s[3]));
        atomicMax(&vmax_bits[plane], __float_as_uint(m));  // non-neg: uint order == float order
    }
}

// ---------------- Pass 2: NMS ----------------
__global__ __launch_bounds__(256) void nms_kernel(const float* __restrict__ in,
                                                  const unsigned int* __restrict__ vmax_bits,
                                                  float* __restrict__ out, int N) {
    // XCD-chunked swizzle: 4096 workgroups = 8 XCDs x 512. Hardware dispatch is
    // x-fastest round-robin over XCDs; remap so each XCD owns a contiguous range
    // of (plane, band) -> a plane's 32 bands share one XCD's L2 (halo + ctr hits).
    const int hwid = blockIdx.x + (blockIdx.y << 5);     // 0..4095
    const int wg = ((hwid & 7) << 9) + (hwid >> 3);      // bijective (4096 % 8 == 0)
    const int plane = wg >> 5;
    const int ty0 = (wg & 31) * TH;

    const float* pin = in + (size_t)plane * PLANE_ELEMS;

    __shared__ __align__(16) float sRow[LROWS * W];  // 45056 B -> 3 blocks/CU

    const int wid = threadIdx.x >> 6;   // wave 0..3
    const int lane = threadIdx.x & 63;
    const int c8 = lane << 3;           // 8 columns per lane; one wave = one full row

    // Phase A0: issue ALL row loads up front (independent dwordx4's -> one
    // latency wait instead of 5-6 serial ones per wave).
    float4 va[6], vb[6];
    #pragma unroll
    for (int k = 0; k < 6; ++k) {
        const int r = wid + (k << 2);
        if (r < LROWS) {
            const int gy = ty0 + r - 3;
            if (gy >= 0 && gy < H) {
                const float4* row = (const float4*)(pin + (size_t)gy * W);
                va[k] = row[lane * 2];
                vb[k] = row[lane * 2 + 1];
            } else {
                va[k] = vb[k] = make_float4(NEG_INF, NEG_INF, NEG_INF, NEG_INF);
            }
        }
    }

    // Phase A1: horizontal 7-max entirely in registers (shuffle halo).
    #pragma unroll
    for (int k = 0; k < 6; ++k) {
        const int r = wid + (k << 2);
        if (r < LROWS) {   // wave-uniform guard: shuffles below are safe
            float4 v0 = va[k], v1 = vb[k];
            // left neighbor's last 3 cols (its v1.y/z/w), right neighbor's first 3 (v0.x/y/z)
            float l0 = __shfl_up(v1.y, 1, 64), l1 = __shfl_up(v1.z, 1, 64), l2 = __shfl_up(v1.w, 1, 64);
            float r0 = __shfl_down(v0.x, 1, 64), r1 = __shfl_down(v0.y, 1, 64), r2 = __shfl_down(v0.z, 1, 64);
            if (lane == 0) { l0 = NEG_INF; l1 = NEG_INF; l2 = NEG_INF; }
            if (lane == 63) { r0 = NEG_INF; r1 = NEG_INF; r2 = NEG_INF; }
            float a[14] = {l0, l1, l2, v0.x, v0.y, v0.z, v0.w, v1.x, v1.y, v1.z, v1.w, r0, r1, r2};
            // van Herk: rm[j] = max(a[j..j+6]), j=0..7; split at a[7]
            float A[7];
            A[6] = a[6];
            #pragma unroll
            for (int j = 5; j >= 0; --j) A[j] = fmaxf(a[j], A[j + 1]);
            float rm[8];
            rm[0] = A[0];
            float B = a[7];
            rm[1] = fmaxf(A[1], B);
            #pragma unroll
            for (int j = 2; j <= 6; ++j) { B = fmaxf(B, a[6 + j]); rm[j] = fmaxf(A[j], B); }
            B = fmaxf(B, a[13]);
            rm[7] = B;
            float4* dst = (float4*)&sRow[r * W + c8];
            dst[0] = make_float4(rm[0], rm[1], rm[2], rm[3]);
            dst[1] = make_float4(rm[4], rm[5], rm[6], rm[7]);
        }
    }

    // Phase B thread mapping (needed for ctr prefetch).
    const int strip = threadIdx.x >> 7;       // 0/1 -> rows 0..7 / 8..15
    const int cg = threadIdx.x & 127;
    const int c = cg << 2;
    const int y0 = strip << 3;
    const int gy_base = ty0 + y0;

    // Prefetch center values BEFORE the barrier: independent of LDS contents,
    // so the ~L2 latency hides under the barrier + LDS reads.
    float4 ctr[8];
    #pragma unroll
    for (int i = 0; i < 8; ++i) {
        ctr[i] = *(const float4*)(pin + (size_t)(gy_base + i) * W + c);
    }

    const float vmax = __uint_as_float(vmax_bits[plane]);
    const float rel_thr = 0.05f * vmax;
    const float inv_vmax = 1.0f / vmax;

    __syncthreads();

    float* __restrict__ omask = out;
    float* __restrict__ oabs = out + (size_t)N;
    float* __restrict__ orel = out + 2 * (size_t)N;

    // Phase B: vertical 7-max (van Herk over 14 rows -> 8 outputs per thread).
    float4 Lr[7], Aq[7];
    #pragma unroll
    for (int k = 0; k < 7; ++k) Lr[k] = *(const float4*)&sRow[(y0 + k) * W + c];
    Aq[6] = Lr[6];
    #pragma unroll
    for (int j = 5; j >= 0; --j) Aq[j] = vmax4(Lr[j], Aq[j + 1]);

    float4 Bq;
    #pragma unroll
    for (int i = 0; i < 8; ++i) {
        float4 m;
        if (i == 0) {
            m = Aq[0];
        } else {
            float4 row = *(const float4*)&sRow[(y0 + 6 + i) * W + c];
            Bq = (i == 1) ? row : vmax4(Bq, row);
            m = (i == 7) ? Bq : vmax4(Aq[i], Bq);
        }
        const int gy = gy_base + i;
        const float4 cc = ctr[i];
        const bool p0 = (m.x == cc.x) & (cc.x > 0.2f) & (cc.x > rel_thr);
        const bool p1 = (m.y == cc.y) & (cc.y > 0.2f) & (cc.y > rel_thr);
        const bool p2 = (m.z == cc.z) & (cc.z > 0.2f) & (cc.z > rel_thr);
        const bool p3 = (m.w == cc.w) & (cc.w > 0.2f) & (cc.w > rel_thr);
        const float a0 = p0 ? cc.x : 0.0f, a1 = p1 ? cc.y : 0.0f;
        const float a2 = p2 ? cc.z : 0.0f, a3 = p3 ? cc.w : 0.0f;
        const size_t o = (size_t)plane * PLANE_ELEMS + (size_t)gy * W + c;
        nt_store4(omask + o, p0 ? 1.0f : 0.0f, p1 ? 1.0f : 0.0f,
                             p2 ? 1.0f : 0.0f, p3 ? 1.0f : 0.0f);
        nt_store4(oabs + o, a0, a1, a2, a3);
        nt_store4(orel + o, a0 * inv_vmax, a1 * inv_vmax, a2 * inv_vmax, a3 * inv_vmax);
    }
}

extern "C" void kernel_launch(void* const* d_in, const int* in_sizes, int n_in,
                              void* d_out, int out_size, void* d_ws, size_t ws_size,
                              hipStream_t stream) {
    const float* in = (const float*)d_in[0];
    float* out = (float*)d_out;
    const int N = in_sizes[0];           // 33554432
    const int planes = N / PLANE_ELEMS;  // 128

    unsigned int* vmax_bits = (unsigned int*)d_ws;
    (void)hipMemsetAsync(vmax_bits, 0, planes * sizeof(unsigned int), stream);

    vmax_kernel<<<dim3(4, planes), 256, 0, stream>>>(in, vmax_bits);
    nms_kernel<<<dim3(H / TH, planes), 256, 0, stream>>>(in, vmax_bits, out, N);
}

// Round 2
// 477.064 us; speedup vs baseline: 1.0307x; 1.0200x over previous
//
#include <hip/hip_runtime.h>
#include <math.h>

// BeliveMapsNMS: 7x7 same-padded max-pool NMS on [32,4,512,512] f32.
// Outputs (concat flat): mask(0/1 f32), scores_abs, scores_rel.
// R2: occupancy round.
//  - vmax: 2048 blocks (16 chunks/plane), 16 unrolled float4 loads/thread,
//    partials to workspace (no memset, no atomics; one fewer dispatch).
//  - nms: TH=8 -> LDS 28 KB -> 4+ blocks/CU (was 3), __launch_bounds__(256,4).
//  - keeps R1 structure: register row loads, shuffle van Herk, pre-barrier ctr,
//    XCD-chunked swizzle, NT stores.

#define H 512
#define W 512
#define PLANE_ELEMS (H * W)   // 262144
#define TH 8                  // output rows per block
#define LROWS (TH + 6)        // 14 loaded rows
#define NEG_INF (-INFINITY)
#define VCHUNKS 16            // vmax chunks per plane

typedef float v4f __attribute__((ext_vector_type(4)));  // native vec for nontemporal

__device__ __forceinline__ float4 vmax4(float4 a, float4 b) {
    return make_float4(fmaxf(a.x, b.x), fmaxf(a.y, b.y), fmaxf(a.z, b.z), fmaxf(a.w, b.w));
}

__device__ __forceinline__ void nt_store4(float* p, float a, float b, float c, float d) {
    v4f v = {a, b, c, d};
    __builtin_nontemporal_store(v, (v4f*)p);
}

// ---------------- Pass 1: per-plane max (partials, no atomics) ----------------
__global__ __launch_bounds__(256) void vmax_kernel(const float* __restrict__ in,
                                                   float* __restrict__ partials) {
    const int chunk = blockIdx.x;  // 16 chunks of 16384 floats
    const int plane = blockIdx.y;  // 128 planes
    const float4* p = (const float4*)(in + (size_t)plane * PLANE_ELEMS) + chunk * 4096;
    // 16 independent float4 loads per thread, fully unrolled -> deep MLP.
    float4 v[16];
    #pragma unroll
    for (int j = 0; j < 16; ++j) v[j] = p[threadIdx.x + (j << 8)];
    float4 t[8];
    #pragma unroll
    for (int j = 0; j < 8; ++j) t[j] = vmax4(v[j], v[j + 8]);
    #pragma unroll
    for (int j = 0; j < 4; ++j) t[j] = vmax4(t[j], t[j + 4]);
    float4 q = vmax4(vmax4(t[0], t[1]), vmax4(t[2], t[3]));
    float m = fmaxf(fmaxf(q.x, q.y), fmaxf(q.z, q.w));
    #pragma unroll
    for (int o = 32; o > 0; o >>= 1) m = fmaxf(m, __shfl_down(m, o, 64));
    __shared__ float s[4];
    if ((threadIdx.x & 63) == 0) s[threadIdx.x >> 6] = m;
    __syncthreads();
    if (threadIdx.x == 0) {
        // inputs non-negative; every slot written each launch -> no init needed
        partials[(plane << 4) + chunk] = fmaxf(fmaxf(s[0], s[1]), fmaxf(s[2], s[3]));
    }
}

// ---------------- Pass 2: NMS ----------------
__global__ __launch_bounds__(256, 4) void nms_kernel(const float* __restrict__ in,
                                                     const float* __restrict__ partials,
                                                     float* __restrict__ out, int N) {
    // XCD-chunked swizzle: 8192 workgroups = 8 XCDs x 1024 (bijective, 8192%8==0).
    const int hwid = blockIdx.x + (blockIdx.y << 6);     // gridDim.x = 64 bands
    const int wg = ((hwid & 7) << 10) + (hwid >> 3);
    const int plane = wg >> 6;
    const int ty0 = (wg & 63) * TH;

    const float* pin = in + (size_t)plane * PLANE_ELEMS;

    __shared__ __align__(16) float sRow[LROWS * W];  // 28672 B -> 4-5 blocks/CU

    const int wid = threadIdx.x >> 6;   // wave 0..3
    const int lane = threadIdx.x & 63;
    const int c8 = lane << 3;           // 8 columns per lane; one wave = one full row

    // Plane max from the 16 partials (one cacheline, broadcast; issued early).
    float pm[16];
    #pragma unroll
    for (int j = 0; j < 16; ++j) pm[j] = partials[(plane << 4) + j];

    // Phase A0: issue all row loads up front (independent dwordx4's).
    float4 va[4], vb[4];
    #pragma unroll
    for (int k = 0; k < 4; ++k) {
        const int r = wid + (k << 2);
        if (r < LROWS) {
            const int gy = ty0 + r - 3;
            if (gy >= 0 && gy < H) {
                const float4* row = (const float4*)(pin + (size_t)gy * W);
                va[k] = row[lane * 2];
                vb[k] = row[lane * 2 + 1];
            } else {
                va[k] = vb[k] = make_float4(NEG_INF, NEG_INF, NEG_INF, NEG_INF);
            }
        }
    }

    // Phase A1: horizontal 7-max entirely in registers (shuffle halo).
    #pragma unroll
    for (int k = 0; k < 4; ++k) {
        const int r = wid + (k << 2);
        if (r < LROWS) {   // wave-uniform guard: shuffles below are safe
            float4 v0 = va[k], v1 = vb[k];
            float l0 = __shfl_up(v1.y, 1, 64), l1 = __shfl_up(v1.z, 1, 64), l2 = __shfl_up(v1.w, 1, 64);
            float r0 = __shfl_down(v0.x, 1, 64), r1 = __shfl_down(v0.y, 1, 64), r2 = __shfl_down(v0.z, 1, 64);
            if (lane == 0) { l0 = NEG_INF; l1 = NEG_INF; l2 = NEG_INF; }
            if (lane == 63) { r0 = NEG_INF; r1 = NEG_INF; r2 = NEG_INF; }
            float a[14] = {l0, l1, l2, v0.x, v0.y, v0.z, v0.w, v1.x, v1.y, v1.z, v1.w, r0, r1, r2};
            // van Herk: rm[j] = max(a[j..j+6]), j=0..7; split at a[7]
            float A[7];
            A[6] = a[6];
            #pragma unroll
            for (int j = 5; j >= 0; --j) A[j] = fmaxf(a[j], A[j + 1]);
            float rm[8];
            rm[0] = A[0];
            float B = a[7];
            rm[1] = fmaxf(A[1], B);
            #pragma unroll
            for (int j = 2; j <= 6; ++j) { B = fmaxf(B, a[6 + j]); rm[j] = fmaxf(A[j], B); }
            B = fmaxf(B, a[13]);
            rm[7] = B;
            float4* dst = (float4*)&sRow[r * W + c8];
            dst[0] = make_float4(rm[0], rm[1], rm[2], rm[3]);
            dst[1] = make_float4(rm[4], rm[5], rm[6], rm[7]);
        }
    }

    // Phase B thread mapping.
    const int strip = threadIdx.x >> 7;       // 0/1 -> rows 0..3 / 4..7
    const int cg = threadIdx.x & 127;
    const int c = cg << 2;
    const int y0 = strip << 2;
    const int gy_base = ty0 + y0;

    // Prefetch center values BEFORE the barrier (L3/L2-hot after vmax pass).
    float4 ctr[4];
    #pragma unroll
    for (int i = 0; i < 4; ++i) {
        ctr[i] = *(const float4*)(pin + (size_t)(gy_base + i) * W + c);
    }

    // Reduce plane max (exact: fmax over disjoint chunks).
    float vmax = pm[0];
    #pragma unroll
    for (int j = 1; j < 16; ++j) vmax = fmaxf(vmax, pm[j]);
    const float rel_thr = 0.05f * vmax;
    const float inv_vmax = 1.0f / vmax;

    __syncthreads();

    float* __restrict__ omask = out;
    float* __restrict__ oabs = out + (size_t)N;
    float* __restrict__ orel = out + 2 * (size_t)N;

    // Phase B: vertical 7-max (van Herk over 10 rows -> 4 outputs per thread).
    float4 Lr[7];
    #pragma unroll
    for (int k = 0; k < 7; ++k) Lr[k] = *(const float4*)&sRow[(y0 + k) * W + c];
    float4 Aq[4];
    {
        float4 suf = vmax4(Lr[4], vmax4(Lr[5], Lr[6]));
        Aq[3] = vmax4(Lr[3], suf);
        Aq[2] = vmax4(Lr[2], Aq[3]);
        Aq[1] = vmax4(Lr[1], Aq[2]);
        Aq[0] = vmax4(Lr[0], Aq[1]);
    }

    float4 Bq;
    #pragma unroll
    for (int i = 0; i < 4; ++i) {
        float4 m;
        if (i == 0) {
            m = Aq[0];
        } else {
            float4 row = *(const float4*)&sRow[(y0 + 6 + i) * W + c];
            Bq = (i == 1) ? row : vmax4(Bq, row);
            m = vmax4(Aq[i], Bq);
        }
        const int gy = gy_base + i;
        const float4 cc = ctr[i];
        const bool p0 = (m.x == cc.x) & (cc.x > 0.2f) & (cc.x > rel_thr);
        const bool p1 = (m.y == cc.y) & (cc.y > 0.2f) & (cc.y > rel_thr);
        const bool p2 = (m.z == cc.z) & (cc.z > 0.2f) & (cc.z > rel_thr);
        const bool p3 = (m.w == cc.w) & (cc.w > 0.2f) & (cc.w > rel_thr);
        const float a0 = p0 ? cc.x : 0.0f, a1 = p1 ? cc.y : 0.0f;
        const float a2 = p2 ? cc.z : 0.0f, a3 = p3 ? cc.w : 0.0f;
        const size_t o = (size_t)plane * PLANE_ELEMS + (size_t)gy * W + c;
        nt_store4(omask + o, p0 ? 1.0f : 0.0f, p1 ? 1.0f : 0.0f,
                             p2 ? 1.0f : 0.0f, p3 ? 1.0f : 0.0f);
        nt_store4(oabs + o, a0, a1, a2, a3);
        nt_store4(orel + o, a0 * inv_vmax, a1 * inv_vmax, a2 * inv_vmax, a3 * inv_vmax);
    }
}

extern "C" void kernel_launch(void* const* d_in, const int* in_sizes, int n_in,
                              void* d_out, int out_size, void* d_ws, size_t ws_size,
                              hipStream_t stream) {
    const float* in = (const float*)d_in[0];
    float* out = (float*)d_out;
    const int N = in_sizes[0];           // 33554432
    const int planes = N / PLANE_ELEMS;  // 128

    float* partials = (float*)d_ws;      // 128*16 floats = 8 KB

    vmax_kernel<<<dim3(VCHUNKS, planes), 256, 0, stream>>>(in, partials);
    nms_kernel<<<dim3(H / TH, planes), 256, 0, stream>>>(in, partials, out, N);
}